// Round 4
// baseline (475.616 us; speedup 1.0000x reference)
//
#include <hip/hip_runtime.h>
#include <hip/hip_fp16.h>

#define NN 100000      // nodes
#define NE 1600000     // edges
#define INF 32
#define HF 32
#define CF 8

#define BNODE 128                       // nodes per bucket
#define NBKT ((NN + BNODE - 1) / BNODE) // 782
#define CAP 3072                        // slots per bucket (mean 2048, +22 sigma)
#define CHUNK 8192                      // edges per bin block
#define P1BLK ((NE + CHUNK - 1) / CHUNK)

// ---------------- K1: bin edges by dst bucket + deg_out histogram ----------------
__global__ void __launch_bounds__(256) bin_kernel(
        const int* __restrict__ src, const int* __restrict__ dst,
        int* __restrict__ deg_out, int* __restrict__ gcur,
        unsigned int* __restrict__ bins) {
    __shared__ int cnt[NBKT];
    __shared__ int base[NBKT];
    for (int i = threadIdx.x; i < NBKT; i += 256) cnt[i] = 0;
    __syncthreads();
    int e0 = blockIdx.x * CHUNK;
    int e1 = min(e0 + CHUNK, NE);
    // phase A: count buckets + out-degree histogram
    for (int e = e0 + threadIdx.x; e < e1; e += 256) {
        atomicAdd(&cnt[dst[e] >> 7], 1);
        atomicAdd(&deg_out[src[e]], 1);
    }
    __syncthreads();
    // phase B: reserve contiguous space per bucket
    for (int i = threadIdx.x; i < NBKT; i += 256) {
        base[i] = atomicAdd(&gcur[i], cnt[i]);
        cnt[i] = 0;
    }
    __syncthreads();
    // phase C: write packed payloads (local_dst<<17 | src)
    for (int e = e0 + threadIdx.x; e < e1; e += 256) {
        int d = dst[e], s = src[e];
        int b = d >> 7;
        int off = base[b] + atomicAdd(&cnt[b], 1);
        if (off < CAP)
            bins[(size_t)b * CAP + off] = ((unsigned)(d & 127) << 17) | (unsigned)s;
    }
}

// ---------------- K2: h = (x @ W1) * rsqrt(deg_out), packed f16 pairs ----------------
__global__ void xw1_kernel(const float* __restrict__ x, const float* __restrict__ W1,
                           const int* __restrict__ deg_out, unsigned int* __restrict__ h) {
    __shared__ float w[INF * HF];
    for (int i = threadIdx.x; i < INF * HF; i += blockDim.x) w[i] = W1[i];
    __syncthreads();
    int n = blockIdx.x * blockDim.x + threadIdx.x;
    if (n >= NN) return;

    float xr[INF];
    const float4* xp = (const float4*)(x + (size_t)n * INF);
    #pragma unroll
    for (int i = 0; i < INF / 4; ++i) {
        float4 v = xp[i];
        xr[4*i+0] = v.x; xr[4*i+1] = v.y; xr[4*i+2] = v.z; xr[4*i+3] = v.w;
    }
    float acc[HF];
    #pragma unroll
    for (int c = 0; c < HF; ++c) acc[c] = 0.0f;
    #pragma unroll
    for (int k = 0; k < INF; ++k) {
        float xv = xr[k];
        #pragma unroll
        for (int c = 0; c < HF; ++c) acc[c] = fmaf(xv, w[k * HF + c], acc[c]);
    }
    float rs = rsqrtf(fmaxf((float)deg_out[n], 1.0f));
    unsigned int pk[HF / 2];
    #pragma unroll
    for (int i = 0; i < HF / 2; ++i) {
        __half2 p = __floats2half2_rn(acc[2*i] * rs, acc[2*i+1] * rs);
        pk[i] = *(unsigned int*)&p;
    }
    uint4* hp = (uint4*)(h + (size_t)n * (HF / 2));
    #pragma unroll
    for (int i = 0; i < 4; ++i) {
        uint4 v;
        v.x = pk[4*i+0]; v.y = pk[4*i+1]; v.z = pk[4*i+2]; v.w = pk[4*i+3];
        hp[i] = v;
    }
}

// ---------------- K3: per-bucket gather + LDS f32 accumulate + fused layer-1 tail ----------------
// y[n] = rs_out[n] * relu(agg[n]*rs_in[n] + b1) ; wgt[src] += rs_in[dst]
__global__ void __launch_bounds__(256) bucket_kernel(
        const unsigned int* __restrict__ bins, const int* __restrict__ gcur,
        const unsigned int* __restrict__ h, const int* __restrict__ deg_out,
        const float* __restrict__ b1,
        float* __restrict__ wgt, float* __restrict__ y) {
    __shared__ float agg[BNODE * 36];   // pad 32->36: spreads banks for random-node atomics
    __shared__ int cnt[BNODE];
    for (int i = threadIdx.x; i < BNODE * 36; i += 256) agg[i] = 0.f;
    for (int i = threadIdx.x; i < BNODE; i += 256) cnt[i] = 0;
    __syncthreads();

    const int b = blockIdx.x;
    const int m = min(gcur[b], CAP);
    const unsigned int* bb = bins + (size_t)b * CAP;
    const int lane8 = threadIdx.x & 7;
    const int g = threadIdx.x >> 3;     // 0..31: edge / node group

    float b1r[4];
    #pragma unroll
    for (int c = 0; c < 4; ++c) b1r[c] = b1[lane8 * 4 + c];

    // phase A: 8 lanes per edge — coalesced 64B h-row gather, LDS f32 atomic accumulate
    for (int j = g; j < m; j += 32) {
        unsigned p = bb[j];
        int s = p & 0x1FFFF;
        int local = p >> 17;
        if (lane8 == 0) atomicAdd(&cnt[local], 1);
        uint2 hv = *(const uint2*)(h + (size_t)s * 16 + lane8 * 2);
        float2 lo = __half22float2(*(__half2*)&hv.x);
        float2 hi = __half22float2(*(__half2*)&hv.y);
        float* ap = agg + local * 36 + lane8 * 4;
        atomicAdd(ap + 0, lo.x);
        atomicAdd(ap + 1, lo.y);
        atomicAdd(ap + 2, hi.x);
        atomicAdd(ap + 3, hi.y);
    }
    __syncthreads();

    // phase B: wgt[src] += rs_in[dst]  (the only remaining per-edge global atomic)
    for (int j = threadIdx.x; j < m; j += 256) {
        unsigned p = bb[j];
        int s = p & 0x1FFFF;
        int local = p >> 17;
        float rs_in = rsqrtf(fmaxf((float)cnt[local], 1.0f));
        atomicAdd(&wgt[s], rs_in);
    }

    // phase C: per-node fused tail, coalesced y write (8 lanes x float4 = 128B row)
    for (int local = g; local < BNODE; local += 32) {
        int n = b * BNODE + local;
        if (n >= NN) continue;
        float rs_in  = rsqrtf(fmaxf((float)cnt[local], 1.0f));
        float rs_out = rsqrtf(fmaxf((float)deg_out[n], 1.0f));
        const float* ap = agg + local * 36 + lane8 * 4;
        float4 o;
        o.x = rs_out * fmaxf(fmaf(ap[0], rs_in, b1r[0]), 0.f);
        o.y = rs_out * fmaxf(fmaf(ap[1], rs_in, b1r[1]), 0.f);
        o.z = rs_out * fmaxf(fmaf(ap[2], rs_in, b1r[2]), 0.f);
        o.w = rs_out * fmaxf(fmaf(ap[3], rs_in, b1r[3]), 0.f);
        *(float4*)(y + (size_t)n * HF + lane8 * 4) = o;
    }
}

// ---------------- K4: v[32] = sum_n wgt[n] * y[n] ----------------
__global__ void __launch_bounds__(256) reduce_kernel(
        const float* __restrict__ y, const float* __restrict__ wgt,
        float* __restrict__ v) {
    const int lane8 = threadIdx.x & 7;
    const int f0 = lane8 * 4;
    const int group = (blockIdx.x * blockDim.x + threadIdx.x) >> 3;
    const int ngroups = (gridDim.x * blockDim.x) >> 3;

    float vacc[4] = {0.f, 0.f, 0.f, 0.f};
    for (int n = group; n < NN; n += ngroups) {
        float w = wgt[n];
        if (w != 0.f) {
            float4 yv = *(const float4*)(y + (size_t)n * HF + f0);
            vacc[0] += w * yv.x; vacc[1] += w * yv.y;
            vacc[2] += w * yv.z; vacc[3] += w * yv.w;
        }
    }
    #pragma unroll
    for (int c = 0; c < 4; ++c) {
        vacc[c] += __shfl_xor(vacc[c], 8, 64);
        vacc[c] += __shfl_xor(vacc[c], 16, 64);
        vacc[c] += __shfl_xor(vacc[c], 32, 64);
    }
    __shared__ float vl[32];
    if (threadIdx.x < 32) vl[threadIdx.x] = 0.f;
    __syncthreads();
    if ((threadIdx.x & 63) < 8) {
        #pragma unroll
        for (int c = 0; c < 4; ++c) atomicAdd(&vl[f0 + c], vacc[c]);
    }
    __syncthreads();
    if (threadIdx.x < 32) atomicAdd(&v[threadIdx.x], vl[threadIdx.x]);
}

// ---------------- K5: out = (v @ W2)/N + b2 ----------------
__global__ void final_kernel(const float* __restrict__ v, const float* __restrict__ W2,
                             const float* __restrict__ b2, float* __restrict__ out) {
    int c = threadIdx.x;
    if (c < CF) {
        float s = 0.f;
        #pragma unroll
        for (int k = 0; k < HF; ++k) s = fmaf(v[k], W2[k * CF + c], s);
        out[c] = s * (1.0f / NN) + b2[c];
    }
}

static inline size_t align256(size_t x) { return (x + 255) & ~(size_t)255; }

extern "C" void kernel_launch(void* const* d_in, const int* in_sizes, int n_in,
                              void* d_out, int out_size, void* d_ws, size_t ws_size,
                              hipStream_t stream) {
    const float* x   = (const float*)d_in[0];
    const int*   src = (const int*)  d_in[1];
    const int*   dst = (const int*)  d_in[2];
    const float* W1  = (const float*)d_in[3];
    const float* b1  = (const float*)d_in[4];
    const float* W2  = (const float*)d_in[5];
    const float* b2  = (const float*)d_in[6];
    float* out = (float*)d_out;

    char* base = (char*)d_ws;
    size_t off = 0;
    int* deg_out = (int*)(base + off);           off = align256(off + NN * 4);
    float* wgt   = (float*)(base + off);         off = align256(off + NN * 4);
    int* gcur    = (int*)(base + off);           off = align256(off + NBKT * 4);
    float* v     = (float*)(base + off);         off = align256(off + 32 * 4);
    size_t zero_bytes = off;                     // everything above starts at 0
    unsigned int* h    = (unsigned int*)(base + off); off = align256(off + (size_t)NN * 16 * 4);
    unsigned int* bins = (unsigned int*)(base + off); off = align256(off + (size_t)NBKT * CAP * 4);
    float* y           = (float*)(base + off);   off = align256(off + (size_t)NN * HF * 4);

    hipMemsetAsync(base, 0, zero_bytes, stream);

    const int B = 256;
    bin_kernel<<<P1BLK, B, 0, stream>>>(src, dst, deg_out, gcur, bins);
    xw1_kernel<<<(NN + B - 1) / B, B, 0, stream>>>(x, W1, deg_out, h);
    bucket_kernel<<<NBKT, B, 0, stream>>>(bins, gcur, h, deg_out, b1, wgt, y);
    reduce_kernel<<<1024, B, 0, stream>>>(y, wgt, v);
    final_kernel<<<1, 64, 0, stream>>>(v, W2, b2, out);
}